// Round 1
// baseline (4137.769 us; speedup 1.0000x reference)
//
#include <hip/hip_runtime.h>
#include <math.h>

#define N_NODES 60000
#define N_EDGES 600000
#define B_GRAPHS 512
#define DIM 128
#define RBF_R 30
#define NLAYERS 3
#define NBINS 4096

__device__ __forceinline__ float sp05(float x) {
    // softplus beta=0.5 threshold=14: x if 0.5x>14 else 2*log1p(exp(0.5x))
    float bx = 0.5f * x;
    return bx > 14.0f ? x : 2.0f * log1pf(expf(bx));
}

__device__ __forceinline__ float sp1(float x) {
    // softplus beta=1 threshold=20
    return x > 20.0f ? x : log1pf(expf(x));
}

// h0[n,d] = node_emb[atom_type[n], d]
__global__ void k_embed(const int* __restrict__ atom_type,
                        const float* __restrict__ node_emb,
                        float* __restrict__ h0) {
    int i = blockIdx.x * blockDim.x + threadIdx.x;
    if (i >= N_NODES * DIM) return;
    int n = i >> 7, d = i & 127;
    h0[i] = node_emb[atom_type[n] * DIM + d];
}

// Tabulate edge MLP: table[b][d] = ((sp05(rbf(d_b)@Wc1+bc1))@Wc2+bc2)@Wc3+bc3
// One block (128 threads) per bin; NBINS+1 bins for lerp upper edge.
__global__ void k_table(const float* __restrict__ Wc1, const float* __restrict__ bc1,
                        const float* __restrict__ Wc2, const float* __restrict__ bc2,
                        const float* __restrict__ Wc3, const float* __restrict__ bc3,
                        float* __restrict__ table) {
    __shared__ float t[DIM];
    __shared__ float u[DIM];
    int b = blockIdx.x;
    int d = threadIdx.x;
    float dist = (float)b * (10.0f / (float)NBINS);
    const float gap = 10.0f / 29.0f;
    float acc = bc1[d];
#pragma unroll
    for (int k = 0; k < RBF_R; ++k) {
        float c = (float)k * (10.0f / 29.0f);
        float df = dist - c;
        acc += expf(-df * df / gap) * Wc1[k * DIM + d];
    }
    t[d] = sp05(acc);
    __syncthreads();
    acc = bc2[d];
#pragma unroll 8
    for (int k = 0; k < DIM; ++k) acc += t[k] * Wc2[k * DIM + d];
    u[d] = acc;
    __syncthreads();
    acc = bc3[d];
#pragma unroll 8
    for (int k = 0; k < DIM; ++k) acc += u[k] * Wc3[k * DIM + d];
    table[b * DIM + d] = acc;
}

// G = X @ W + bias + 1   (the "+1" from msg = (h_new[src]+1)*e folded in)
// 4 rows per block of 256 threads; each thread computes 2 outputs.
__global__ void k_gemm_g(const float* __restrict__ X, const float* __restrict__ W,
                         const float* __restrict__ bias, float* __restrict__ G) {
    __shared__ float xs[4 * DIM];
    int rb = blockIdx.x * 4;
    int tid = threadIdx.x;
    for (int i = tid; i < 4 * DIM; i += 256) {
        int r = i >> 7, d = i & 127;
        xs[i] = X[(size_t)(rb + r) * DIM + d];
    }
    __syncthreads();
    int col = tid & 127;
    int r0 = tid >> 7; // 0 or 1
    float acc0 = bias[col] + 1.0f;
    float acc1 = acc0;
#pragma unroll 8
    for (int k = 0; k < DIM; ++k) {
        float w = W[k * DIM + col];
        acc0 += xs[r0 * DIM + k] * w;
        acc1 += xs[(r0 + 2) * DIM + k] * w;
    }
    G[(size_t)(rb + r0) * DIM + col] = acc0;
    G[(size_t)(rb + r0 + 2) * DIM + col] = acc1;
}

// Per-edge: e_feat = lerp(table, dist); msg = g[src]*e_feat; atomic scatter to node[dst].
// 32 threads per edge, 4 floats per thread.
__global__ void k_edge(const int* __restrict__ src, const int* __restrict__ dst,
                       const float* __restrict__ dist, const float* __restrict__ table,
                       const float* __restrict__ g, float* __restrict__ node) {
    int gid = blockIdx.x * blockDim.x + threadIdx.x;
    int e = gid >> 5;
    if (e >= N_EDGES) return;
    int q = gid & 31;
    int d = q * 4;
    int s = src[e];
    int dd = dst[e];
    float x = dist[e];
    float pos = x * ((float)NBINS / 10.0f);
    int bin = (int)pos;
    if (bin > NBINS - 1) bin = NBINS - 1;
    float w = pos - (float)bin;
    float4 a = *(const float4*)(table + (size_t)bin * DIM + d);
    float4 b = *(const float4*)(table + (size_t)(bin + 1) * DIM + d);
    float4 gv = *(const float4*)(g + (size_t)s * DIM + d);
    float m0 = gv.x * (a.x + w * (b.x - a.x));
    float m1 = gv.y * (a.y + w * (b.y - a.y));
    float m2 = gv.z * (a.z + w * (b.z - a.z));
    float m3 = gv.w * (a.w + w * (b.w - a.w));
    float* np = node + (size_t)dd * DIM + d;
    atomicAdd(np + 0, m0);
    atomicAdd(np + 1, m1);
    atomicAdd(np + 2, m2);
    atomicAdd(np + 3, m3);
}

// h_out = h_in + (sp05(node@W2+b2))@W3 + b3, fused row-wise. 4 rows / 256-thread block.
__global__ void k_node_update(const float* __restrict__ node,
                              const float* __restrict__ W2, const float* __restrict__ b2,
                              const float* __restrict__ W3, const float* __restrict__ b3,
                              const float* __restrict__ h_in, float* __restrict__ h_out) {
    __shared__ float xs[4 * DIM];
    __shared__ float ts[4 * DIM];
    int rb = blockIdx.x * 4;
    int tid = threadIdx.x;
    for (int i = tid; i < 4 * DIM; i += 256) {
        int r = i >> 7, d = i & 127;
        xs[i] = node[(size_t)(rb + r) * DIM + d];
    }
    __syncthreads();
    int col = tid & 127;
    int r0 = tid >> 7;
    float acc0 = b2[col], acc1 = b2[col];
#pragma unroll 8
    for (int k = 0; k < DIM; ++k) {
        float w = W2[k * DIM + col];
        acc0 += xs[r0 * DIM + k] * w;
        acc1 += xs[(r0 + 2) * DIM + k] * w;
    }
    ts[r0 * DIM + col] = sp05(acc0);
    ts[(r0 + 2) * DIM + col] = sp05(acc1);
    __syncthreads();
    acc0 = b3[col];
    acc1 = b3[col];
#pragma unroll 8
    for (int k = 0; k < DIM; ++k) {
        float w = W3[k * DIM + col];
        acc0 += ts[r0 * DIM + k] * w;
        acc1 += ts[(r0 + 2) * DIM + k] * w;
    }
    size_t i0 = (size_t)(rb + r0) * DIM + col;
    size_t i1 = (size_t)(rb + r0 + 2) * DIM + col;
    h_out[i0] = h_in[i0] + acc0;
    h_out[i1] = h_in[i1] + acc1;
}

// Readout: per node n: v_j = sp1(hcat[n]@Wr1 + br1); out_n = v@Wr2 + br2;
// atomicAdd(out[graph_ids[n]], out_n). 4 rows per block; one wave per row.
__global__ void k_readout(const float* __restrict__ h0, const float* __restrict__ h1,
                          const float* __restrict__ h2, const float* __restrict__ h3,
                          const float* __restrict__ Wr1, const float* __restrict__ br1,
                          const float* __restrict__ Wr2, const float* __restrict__ br2,
                          const int* __restrict__ graph_ids, float* __restrict__ out) {
    __shared__ float xs[4 * 512];
    int rb = blockIdx.x * 4;
    int tid = threadIdx.x;
#pragma unroll
    for (int l = 0; l < 4; ++l) {
        const float* hp = (l == 0) ? h0 : (l == 1) ? h1 : (l == 2) ? h2 : h3;
        for (int i = tid; i < 4 * DIM; i += 256) {
            int r = i >> 7, d = i & 127;
            xs[r * 512 + l * DIM + d] = hp[(size_t)(rb + r) * DIM + d];
        }
    }
    __syncthreads();
    int r = tid >> 6; // wave id = local row
    int j = tid & 63;
    float acc = br1[j];
#pragma unroll 8
    for (int k = 0; k < 512; ++k) acc += xs[r * 512 + k] * Wr1[k * 64 + j];
    float v = sp1(acc) * Wr2[j];
#pragma unroll
    for (int off = 32; off > 0; off >>= 1) v += __shfl_down(v, off);
    if (j == 0) {
        int n = rb + r;
        atomicAdd(&out[graph_ids[n]], v + br2[0]);
    }
}

extern "C" void kernel_launch(void* const* d_in, const int* in_sizes, int n_in,
                              void* d_out, int out_size, void* d_ws, size_t ws_size,
                              hipStream_t stream) {
    const int* atom_type   = (const int*)d_in[0];
    const int* src         = (const int*)d_in[1];
    const int* dst         = (const int*)d_in[2];
    const int* graph_ids   = (const int*)d_in[3];
    const float* dist      = (const float*)d_in[4];
    const float* node_emb  = (const float*)d_in[5];
    const float* W_n1 = (const float*)d_in[6];  const float* b_n1 = (const float*)d_in[7];
    const float* W_c1 = (const float*)d_in[8];  const float* b_c1 = (const float*)d_in[9];
    const float* W_c2 = (const float*)d_in[10]; const float* b_c2 = (const float*)d_in[11];
    const float* W_c3 = (const float*)d_in[12]; const float* b_c3 = (const float*)d_in[13];
    const float* W_n2 = (const float*)d_in[14]; const float* b_n2 = (const float*)d_in[15];
    const float* W_n3 = (const float*)d_in[16]; const float* b_n3 = (const float*)d_in[17];
    const float* W_r1 = (const float*)d_in[18]; const float* b_r1 = (const float*)d_in[19];
    const float* W_r2 = (const float*)d_in[20]; const float* b_r2 = (const float*)d_in[21];
    float* out = (float*)d_out;

    float* ws = (float*)d_ws;
    size_t ND = (size_t)N_NODES * DIM;
    float* hs0     = ws;
    float* hs1     = hs0 + ND;
    float* hs2     = hs1 + ND;
    float* hs3     = hs2 + ND;
    float* gbuf    = hs3 + ND;
    float* nodebuf = gbuf + ND;
    float* table   = nodebuf + ND;

    float* hptr[4] = {hs0, hs1, hs2, hs3};

    hipMemsetAsync(out, 0, B_GRAPHS * sizeof(float), stream);
    k_embed<<<(N_NODES * DIM) / 256, 256, 0, stream>>>(atom_type, node_emb, hs0);

    for (int i = 0; i < NLAYERS; ++i) {
        k_table<<<NBINS + 1, DIM, 0, stream>>>(
            W_c1 + (size_t)i * RBF_R * DIM, b_c1 + (size_t)i * DIM,
            W_c2 + (size_t)i * DIM * DIM,  b_c2 + (size_t)i * DIM,
            W_c3 + (size_t)i * DIM * DIM,  b_c3 + (size_t)i * DIM, table);
        k_gemm_g<<<N_NODES / 4, 256, 0, stream>>>(
            hptr[i], W_n1 + (size_t)i * DIM * DIM, b_n1 + (size_t)i * DIM, gbuf);
        hipMemsetAsync(nodebuf, 0, ND * sizeof(float), stream);
        k_edge<<<(N_EDGES * 32) / 256, 256, 0, stream>>>(src, dst, dist, table, gbuf, nodebuf);
        k_node_update<<<N_NODES / 4, 256, 0, stream>>>(
            nodebuf, W_n2 + (size_t)i * DIM * DIM, b_n2 + (size_t)i * DIM,
            W_n3 + (size_t)i * DIM * DIM, b_n3 + (size_t)i * DIM, hptr[i], hptr[i + 1]);
    }
    k_readout<<<N_NODES / 4, 256, 0, stream>>>(
        hs0, hs1, hs2, hs3, W_r1, b_r1, W_r2, b_r2, graph_ids, out);
}

// Round 2
// 1389.541 us; speedup vs baseline: 2.9778x; 2.9778x over previous
//
#include <hip/hip_runtime.h>
#include <math.h>

#define N_NODES 60000
#define N_EDGES 600000
#define B_GRAPHS 512
#define DIM 128
#define RBF_R 30
#define NLAYERS 3
#define NBINS 4096
#define CHUNK 512
#define NCHUNK ((N_NODES + CHUNK - 1) / CHUNK)   // 118

__device__ __forceinline__ float sp05(float x) {
    float bx = 0.5f * x;
    return bx > 14.0f ? x : 2.0f * log1pf(expf(bx));
}

__device__ __forceinline__ float sp1(float x) {
    return x > 20.0f ? x : log1pf(expf(x));
}

// h0[n,d] = node_emb[atom_type[n], d]
__global__ void k_embed(const int* __restrict__ atom_type,
                        const float* __restrict__ node_emb,
                        float* __restrict__ h0) {
    int i = blockIdx.x * blockDim.x + threadIdx.x;
    if (i >= N_NODES * DIM) return;
    int n = i >> 7, d = i & 127;
    h0[i] = node_emb[atom_type[n] * DIM + d];
}

// ---------------- CSR build (once per call) ----------------

__global__ void k_hist(const int* __restrict__ dst, int* __restrict__ counts) {
    int e = blockIdx.x * blockDim.x + threadIdx.x;
    if (e >= N_EDGES) return;
    atomicAdd(&counts[dst[e]], 1);
}

__global__ void k_bsum(const int* __restrict__ counts, int* __restrict__ bsums) {
    __shared__ int red[256];
    int c = blockIdx.x, tid = threadIdx.x;
    int base = c * CHUNK;
    int v = 0;
    for (int i = tid; i < CHUNK; i += 256)
        if (base + i < N_NODES) v += counts[base + i];
    red[tid] = v;
    __syncthreads();
    for (int s = 128; s > 0; s >>= 1) {
        if (tid < s) red[tid] += red[tid + s];
        __syncthreads();
    }
    if (tid == 0) bsums[c] = red[0];
}

__global__ void k_scan_b(int* __restrict__ bsums) {
    __shared__ int sb[NCHUNK];
    int tid = threadIdx.x;
    if (tid < NCHUNK) sb[tid] = bsums[tid];
    __syncthreads();
    if (tid == 0) {
        int run = 0;
        for (int i = 0; i < NCHUNK; ++i) { int v = sb[i]; sb[i] = run; run += v; }
    }
    __syncthreads();
    if (tid < NCHUNK) bsums[tid] = sb[tid];
}

__global__ void k_scan_final(const int* __restrict__ counts, const int* __restrict__ bsums,
                             int* __restrict__ offsets) {
    __shared__ int sc[CHUNK];
    int c = blockIdx.x, tid = threadIdx.x;
    int base = c * CHUNK;
    for (int i = tid; i < CHUNK; i += 256)
        sc[i] = (base + i < N_NODES) ? counts[base + i] : 0;
    __syncthreads();
    if (tid == 0) {
        int run = bsums[c];
        for (int i = 0; i < CHUNK; ++i) { int v = sc[i]; sc[i] = run; run += v; }
    }
    __syncthreads();
    for (int i = tid; i < CHUNK; i += 256)
        if (base + i < N_NODES) offsets[base + i] = sc[i];
    if (c == 0 && tid == 0) offsets[N_NODES] = N_EDGES;
}

// Fill perm-ordered edge meta: for each edge, its slot under its dst node,
// storing (src, bin, lerp weight) so the per-layer gather is pure streaming.
__global__ void k_fill(const int* __restrict__ src, const int* __restrict__ dst,
                       const float* __restrict__ dist,
                       const int* __restrict__ offsets, int* __restrict__ cnt2,
                       int* __restrict__ srcp, int* __restrict__ binp,
                       float* __restrict__ wp) {
    int e = blockIdx.x * blockDim.x + threadIdx.x;
    if (e >= N_EDGES) return;
    int d = dst[e];
    int pos = offsets[d] + atomicAdd(&cnt2[d], 1);
    srcp[pos] = src[e];
    float x = dist[e];
    float p = x * ((float)NBINS / 10.0f);
    int bin = (int)p;
    if (bin > NBINS - 1) bin = NBINS - 1;
    binp[pos] = bin;
    wp[pos] = p - (float)bin;
}

// ---------------- per-layer kernels ----------------

// Tabulate edge MLP on 4097 bins.
__global__ void k_table(const float* __restrict__ Wc1, const float* __restrict__ bc1,
                        const float* __restrict__ Wc2, const float* __restrict__ bc2,
                        const float* __restrict__ Wc3, const float* __restrict__ bc3,
                        float* __restrict__ table) {
    __shared__ float t[DIM];
    __shared__ float u[DIM];
    int b = blockIdx.x;
    int d = threadIdx.x;
    float dist = (float)b * (10.0f / (float)NBINS);
    const float gap = 10.0f / 29.0f;
    float acc = bc1[d];
#pragma unroll
    for (int k = 0; k < RBF_R; ++k) {
        float c = (float)k * (10.0f / 29.0f);
        float df = dist - c;
        acc += expf(-df * df / gap) * Wc1[k * DIM + d];
    }
    t[d] = sp05(acc);
    __syncthreads();
    acc = bc2[d];
#pragma unroll 8
    for (int k = 0; k < DIM; ++k) acc += t[k] * Wc2[k * DIM + d];
    u[d] = acc;
    __syncthreads();
    acc = bc3[d];
#pragma unroll 8
    for (int k = 0; k < DIM; ++k) acc += u[k] * Wc3[k * DIM + d];
    table[b * DIM + d] = acc;
}

// G = X @ W + bias + 1
__global__ void k_gemm_g(const float* __restrict__ X, const float* __restrict__ W,
                         const float* __restrict__ bias, float* __restrict__ G) {
    __shared__ float xs[4 * DIM];
    int rb = blockIdx.x * 4;
    int tid = threadIdx.x;
    for (int i = tid; i < 4 * DIM; i += 256) {
        int r = i >> 7, d = i & 127;
        xs[i] = X[(size_t)(rb + r) * DIM + d];
    }
    __syncthreads();
    int col = tid & 127;
    int r0 = tid >> 7;
    float acc0 = bias[col] + 1.0f;
    float acc1 = acc0;
#pragma unroll 8
    for (int k = 0; k < DIM; ++k) {
        float w = W[k * DIM + col];
        acc0 += xs[r0 * DIM + k] * w;
        acc1 += xs[(r0 + 2) * DIM + k] * w;
    }
    G[(size_t)(rb + r0) * DIM + col] = acc0;
    G[(size_t)(rb + r0 + 2) * DIM + col] = acc1;
}

// Gather: one 128-thread block per node; thread d owns dim d.
// acc_d = sum over incoming edges of g[src][d] * lerp(table, bin, w)[d]
__global__ void k_gather(const int* __restrict__ offsets,
                         const int* __restrict__ srcp, const int* __restrict__ binp,
                         const float* __restrict__ wp,
                         const float* __restrict__ table, const float* __restrict__ g,
                         float* __restrict__ node) {
    __shared__ int s_s[128];
    __shared__ int s_bin[128];
    __shared__ float s_w[128];
    int n = blockIdx.x;
    int d = threadIdx.x;
    int beg = offsets[n], end = offsets[n + 1];
    float acc = 0.0f;
    for (int base = beg; base < end; base += 128) {
        int cnt = min(128, end - base);
        if (d < cnt) {
            s_s[d] = srcp[base + d];
            s_bin[d] = binp[base + d];
            s_w[d] = wp[base + d];
        }
        __syncthreads();
        for (int j = 0; j < cnt; ++j) {
            int s = s_s[j];
            int bin = s_bin[j];
            float w = s_w[j];
            float a = table[(size_t)bin * DIM + d];
            float b = table[(size_t)(bin + 1) * DIM + d];
            float gv = g[(size_t)s * DIM + d];
            acc += gv * (a + w * (b - a));
        }
        __syncthreads();
    }
    node[(size_t)n * DIM + d] = acc;
}

// h_out = h_in + (sp05(node@W2+b2))@W3 + b3
__global__ void k_node_update(const float* __restrict__ node,
                              const float* __restrict__ W2, const float* __restrict__ b2,
                              const float* __restrict__ W3, const float* __restrict__ b3,
                              const float* __restrict__ h_in, float* __restrict__ h_out) {
    __shared__ float xs[4 * DIM];
    __shared__ float ts[4 * DIM];
    int rb = blockIdx.x * 4;
    int tid = threadIdx.x;
    for (int i = tid; i < 4 * DIM; i += 256) {
        int r = i >> 7, d = i & 127;
        xs[i] = node[(size_t)(rb + r) * DIM + d];
    }
    __syncthreads();
    int col = tid & 127;
    int r0 = tid >> 7;
    float acc0 = b2[col], acc1 = b2[col];
#pragma unroll 8
    for (int k = 0; k < DIM; ++k) {
        float w = W2[k * DIM + col];
        acc0 += xs[r0 * DIM + k] * w;
        acc1 += xs[(r0 + 2) * DIM + k] * w;
    }
    ts[r0 * DIM + col] = sp05(acc0);
    ts[(r0 + 2) * DIM + col] = sp05(acc1);
    __syncthreads();
    acc0 = b3[col];
    acc1 = b3[col];
#pragma unroll 8
    for (int k = 0; k < DIM; ++k) {
        float w = W3[k * DIM + col];
        acc0 += ts[r0 * DIM + k] * w;
        acc1 += ts[(r0 + 2) * DIM + k] * w;
    }
    size_t i0 = (size_t)(rb + r0) * DIM + col;
    size_t i1 = (size_t)(rb + r0 + 2) * DIM + col;
    h_out[i0] = h_in[i0] + acc0;
    h_out[i1] = h_in[i1] + acc1;
}

// Readout
__global__ void k_readout(const float* __restrict__ h0, const float* __restrict__ h1,
                          const float* __restrict__ h2, const float* __restrict__ h3,
                          const float* __restrict__ Wr1, const float* __restrict__ br1,
                          const float* __restrict__ Wr2, const float* __restrict__ br2,
                          const int* __restrict__ graph_ids, float* __restrict__ out) {
    __shared__ float xs[4 * 512];
    int rb = blockIdx.x * 4;
    int tid = threadIdx.x;
#pragma unroll
    for (int l = 0; l < 4; ++l) {
        const float* hp = (l == 0) ? h0 : (l == 1) ? h1 : (l == 2) ? h2 : h3;
        for (int i = tid; i < 4 * DIM; i += 256) {
            int r = i >> 7, d = i & 127;
            xs[r * 512 + l * DIM + d] = hp[(size_t)(rb + r) * DIM + d];
        }
    }
    __syncthreads();
    int r = tid >> 6;
    int j = tid & 63;
    float acc = br1[j];
#pragma unroll 8
    for (int k = 0; k < 512; ++k) acc += xs[r * 512 + k] * Wr1[k * 64 + j];
    float v = sp1(acc) * Wr2[j];
#pragma unroll
    for (int off = 32; off > 0; off >>= 1) v += __shfl_down(v, off);
    if (j == 0) {
        int n = rb + r;
        atomicAdd(&out[graph_ids[n]], v + br2[0]);
    }
}

extern "C" void kernel_launch(void* const* d_in, const int* in_sizes, int n_in,
                              void* d_out, int out_size, void* d_ws, size_t ws_size,
                              hipStream_t stream) {
    const int* atom_type   = (const int*)d_in[0];
    const int* src         = (const int*)d_in[1];
    const int* dst         = (const int*)d_in[2];
    const int* graph_ids   = (const int*)d_in[3];
    const float* dist      = (const float*)d_in[4];
    const float* node_emb  = (const float*)d_in[5];
    const float* W_n1 = (const float*)d_in[6];  const float* b_n1 = (const float*)d_in[7];
    const float* W_c1 = (const float*)d_in[8];  const float* b_c1 = (const float*)d_in[9];
    const float* W_c2 = (const float*)d_in[10]; const float* b_c2 = (const float*)d_in[11];
    const float* W_c3 = (const float*)d_in[12]; const float* b_c3 = (const float*)d_in[13];
    const float* W_n2 = (const float*)d_in[14]; const float* b_n2 = (const float*)d_in[15];
    const float* W_n3 = (const float*)d_in[16]; const float* b_n3 = (const float*)d_in[17];
    const float* W_r1 = (const float*)d_in[18]; const float* b_r1 = (const float*)d_in[19];
    const float* W_r2 = (const float*)d_in[20]; const float* b_r2 = (const float*)d_in[21];
    float* out = (float*)d_out;

    float* ws = (float*)d_ws;
    size_t ND = (size_t)N_NODES * DIM;
    float* hs0     = ws;
    float* hs1     = hs0 + ND;
    float* hs2     = hs1 + ND;
    float* hs3     = hs2 + ND;
    float* gbuf    = hs3 + ND;
    float* nodebuf = gbuf + ND;
    float* table   = nodebuf + ND;
    float* after_table = table + (size_t)(NBINS + 1) * DIM;
    int*   offsets = (int*)after_table;            // N_NODES+1
    int*   srcp    = offsets + (N_NODES + 1);      // N_EDGES
    int*   binp    = srcp + N_EDGES;               // N_EDGES
    float* wp      = (float*)(binp + N_EDGES);     // N_EDGES
    // temporaries aliased into nodebuf (fully rewritten by k_gather later)
    int*   counts  = (int*)nodebuf;                // N_NODES
    int*   cnt2    = counts + N_NODES;             // N_NODES
    int*   bsums   = cnt2 + N_NODES;               // NCHUNK

    float* hptr[4] = {hs0, hs1, hs2, hs3};

    hipMemsetAsync(out, 0, B_GRAPHS * sizeof(float), stream);
    hipMemsetAsync(counts, 0, (2 * N_NODES + NCHUNK) * sizeof(int), stream);

    k_embed<<<(N_NODES * DIM) / 256, 256, 0, stream>>>(atom_type, node_emb, hs0);

    // CSR build (dst-sorted edge meta)
    k_hist<<<(N_EDGES + 255) / 256, 256, 0, stream>>>(dst, counts);
    k_bsum<<<NCHUNK, 256, 0, stream>>>(counts, bsums);
    k_scan_b<<<1, 128, 0, stream>>>(bsums);
    k_scan_final<<<NCHUNK, 256, 0, stream>>>(counts, bsums, offsets);
    k_fill<<<(N_EDGES + 255) / 256, 256, 0, stream>>>(src, dst, dist, offsets, cnt2,
                                                      srcp, binp, wp);

    for (int i = 0; i < NLAYERS; ++i) {
        k_table<<<NBINS + 1, DIM, 0, stream>>>(
            W_c1 + (size_t)i * RBF_R * DIM, b_c1 + (size_t)i * DIM,
            W_c2 + (size_t)i * DIM * DIM,  b_c2 + (size_t)i * DIM,
            W_c3 + (size_t)i * DIM * DIM,  b_c3 + (size_t)i * DIM, table);
        k_gemm_g<<<N_NODES / 4, 256, 0, stream>>>(
            hptr[i], W_n1 + (size_t)i * DIM * DIM, b_n1 + (size_t)i * DIM, gbuf);
        k_gather<<<N_NODES, 128, 0, stream>>>(offsets, srcp, binp, wp, table, gbuf, nodebuf);
        k_node_update<<<N_NODES / 4, 256, 0, stream>>>(
            nodebuf, W_n2 + (size_t)i * DIM * DIM, b_n2 + (size_t)i * DIM,
            W_n3 + (size_t)i * DIM * DIM, b_n3 + (size_t)i * DIM, hptr[i], hptr[i + 1]);
    }
    k_readout<<<N_NODES / 4, 256, 0, stream>>>(
        hs0, hs1, hs2, hs3, W_r1, b_r1, W_r2, b_r2, graph_ids, out);
}

// Round 3
// 1110.848 us; speedup vs baseline: 3.7249x; 1.2509x over previous
//
#include <hip/hip_runtime.h>
#include <math.h>

#define N_NODES 60000
#define N_EDGES 600000
#define B_GRAPHS 512
#define DIM 128
#define RBF_R 30
#define NLAYERS 3
#define NBINS 4096
#define CHUNK 512
#define NCHUNK ((N_NODES + CHUNK - 1) / CHUNK)   // 118

__device__ __forceinline__ float sp05(float x) {
    float bx = 0.5f * x;
    return bx > 14.0f ? x : 2.0f * log1pf(expf(bx));
}

__device__ __forceinline__ float sp1(float x) {
    return x > 20.0f ? x : log1pf(expf(x));
}

// h0[n,d] = node_emb[atom_type[n], d]
__global__ void k_embed(const int* __restrict__ atom_type,
                        const float* __restrict__ node_emb,
                        float* __restrict__ h0) {
    int i = blockIdx.x * blockDim.x + threadIdx.x;
    if (i >= N_NODES * DIM) return;
    int n = i >> 7, d = i & 127;
    h0[i] = node_emb[atom_type[n] * DIM + d];
}

// ---------------- CSR build (once per call) ----------------

__global__ void k_hist(const int* __restrict__ dst, int* __restrict__ counts) {
    int e = blockIdx.x * blockDim.x + threadIdx.x;
    if (e >= N_EDGES) return;
    atomicAdd(&counts[dst[e]], 1);
}

__global__ void k_bsum(const int* __restrict__ counts, int* __restrict__ bsums) {
    __shared__ int red[256];
    int c = blockIdx.x, tid = threadIdx.x;
    int base = c * CHUNK;
    int v = 0;
    for (int i = tid; i < CHUNK; i += 256)
        if (base + i < N_NODES) v += counts[base + i];
    red[tid] = v;
    __syncthreads();
    for (int s = 128; s > 0; s >>= 1) {
        if (tid < s) red[tid] += red[tid + s];
        __syncthreads();
    }
    if (tid == 0) bsums[c] = red[0];
}

__global__ void k_scan_b(int* __restrict__ bsums) {
    __shared__ int sb[NCHUNK];
    int tid = threadIdx.x;
    if (tid < NCHUNK) sb[tid] = bsums[tid];
    __syncthreads();
    if (tid == 0) {
        int run = 0;
        for (int i = 0; i < NCHUNK; ++i) { int v = sb[i]; sb[i] = run; run += v; }
    }
    __syncthreads();
    if (tid < NCHUNK) bsums[tid] = sb[tid];
}

__global__ void k_scan_final(const int* __restrict__ counts, const int* __restrict__ bsums,
                             int* __restrict__ offsets) {
    __shared__ int sc[CHUNK];
    int c = blockIdx.x, tid = threadIdx.x;
    int base = c * CHUNK;
    for (int i = tid; i < CHUNK; i += 256)
        sc[i] = (base + i < N_NODES) ? counts[base + i] : 0;
    __syncthreads();
    if (tid == 0) {
        int run = bsums[c];
        for (int i = 0; i < CHUNK; ++i) { int v = sc[i]; sc[i] = run; run += v; }
    }
    __syncthreads();
    for (int i = tid; i < CHUNK; i += 256)
        if (base + i < N_NODES) offsets[base + i] = sc[i];
    if (c == 0 && tid == 0) offsets[N_NODES] = N_EDGES;
}

__global__ void k_fill(const int* __restrict__ src, const int* __restrict__ dst,
                       const float* __restrict__ dist,
                       const int* __restrict__ offsets, int* __restrict__ cnt2,
                       int* __restrict__ srcp, int* __restrict__ binp,
                       float* __restrict__ wp) {
    int e = blockIdx.x * blockDim.x + threadIdx.x;
    if (e >= N_EDGES) return;
    int d = dst[e];
    int pos = offsets[d] + atomicAdd(&cnt2[d], 1);
    srcp[pos] = src[e];
    float x = dist[e];
    float p = x * ((float)NBINS / 10.0f);
    int bin = (int)p;
    if (bin > NBINS - 1) bin = NBINS - 1;
    binp[pos] = bin;
    wp[pos] = p - (float)bin;
}

// ---------------- per-layer kernels ----------------

// Tabulate edge MLP on 4097 bins.
__global__ void k_table(const float* __restrict__ Wc1, const float* __restrict__ bc1,
                        const float* __restrict__ Wc2, const float* __restrict__ bc2,
                        const float* __restrict__ Wc3, const float* __restrict__ bc3,
                        float* __restrict__ table) {
    __shared__ float t[DIM];
    __shared__ float u[DIM];
    int b = blockIdx.x;
    int d = threadIdx.x;
    float dist = (float)b * (10.0f / (float)NBINS);
    const float gap = 10.0f / 29.0f;
    float acc = bc1[d];
#pragma unroll
    for (int k = 0; k < RBF_R; ++k) {
        float c = (float)k * (10.0f / 29.0f);
        float df = dist - c;
        acc += expf(-df * df / gap) * Wc1[k * DIM + d];
    }
    t[d] = sp05(acc);
    __syncthreads();
    acc = bc2[d];
#pragma unroll 8
    for (int k = 0; k < DIM; ++k) acc += t[k] * Wc2[k * DIM + d];
    u[d] = acc;
    __syncthreads();
    acc = bc3[d];
#pragma unroll 8
    for (int k = 0; k < DIM; ++k) acc += u[k] * Wc3[k * DIM + d];
    table[b * DIM + d] = acc;
}

// Tiled GEMM: G = X@W + bias + 1. 32 rows/block, 256 threads, 4x4 per thread.
__global__ void k_gemm_g(const float* __restrict__ X, const float* __restrict__ W,
                         const float* __restrict__ bias, float* __restrict__ G) {
    __shared__ float xs[32 * DIM];
    __shared__ float ws[32 * DIM];
    int rb = blockIdx.x * 32;
    int tid = threadIdx.x;
    int tx = tid & 31;       // cols 4tx..4tx+3
    int ty = tid >> 5;       // rows 4ty..4ty+3
    float4 bv = *(const float4*)&bias[4 * tx];
    float acc[4][4];
#pragma unroll
    for (int r = 0; r < 4; ++r) {
        acc[r][0] = bv.x + 1.0f; acc[r][1] = bv.y + 1.0f;
        acc[r][2] = bv.z + 1.0f; acc[r][3] = bv.w + 1.0f;
    }
    for (int i = tid; i < 32 * DIM; i += 256)
        xs[i] = X[(size_t)(rb + (i >> 7)) * DIM + (i & 127)];
    for (int ks = 0; ks < 4; ++ks) {
        __syncthreads();
        for (int i = tid; i < 32 * DIM; i += 256)
            ws[i] = W[(size_t)(ks * 32 + (i >> 7)) * DIM + (i & 127)];
        __syncthreads();
#pragma unroll
        for (int kk = 0; kk < 32; ++kk) {
            float4 w = *(const float4*)&ws[kk * DIM + 4 * tx];
            int kidx = ks * 32 + kk;
#pragma unroll
            for (int r = 0; r < 4; ++r) {
                float x = xs[(4 * ty + r) * DIM + kidx];
                acc[r][0] += x * w.x; acc[r][1] += x * w.y;
                acc[r][2] += x * w.z; acc[r][3] += x * w.w;
            }
        }
    }
#pragma unroll
    for (int r = 0; r < 4; ++r) {
        float4 o = make_float4(acc[r][0], acc[r][1], acc[r][2], acc[r][3]);
        *(float4*)&G[(size_t)(rb + 4 * ty + r) * DIM + 4 * tx] = o;
    }
}

// Gather: one 128-thread block per node; thread d owns dim d.
__global__ void k_gather(const int* __restrict__ offsets,
                         const int* __restrict__ srcp, const int* __restrict__ binp,
                         const float* __restrict__ wp,
                         const float* __restrict__ table, const float* __restrict__ g,
                         float* __restrict__ node) {
    __shared__ int s_s[128];
    __shared__ int s_bin[128];
    __shared__ float s_w[128];
    int n = blockIdx.x;
    int d = threadIdx.x;
    int beg = offsets[n], end = offsets[n + 1];
    float acc = 0.0f;
    for (int base = beg; base < end; base += 128) {
        int cnt = min(128, end - base);
        if (d < cnt) {
            s_s[d] = srcp[base + d];
            s_bin[d] = binp[base + d];
            s_w[d] = wp[base + d];
        }
        __syncthreads();
        for (int j = 0; j < cnt; ++j) {
            int s = s_s[j];
            int bin = s_bin[j];
            float w = s_w[j];
            float a = table[(size_t)bin * DIM + d];
            float b = table[(size_t)(bin + 1) * DIM + d];
            float gv = g[(size_t)s * DIM + d];
            acc += gv * (a + w * (b - a));
        }
        __syncthreads();
    }
    node[(size_t)n * DIM + d] = acc;
}

// h_out = h_in + (sp05(node@W2+b2))@W3 + b3. Tiled: 32 rows/block.
__global__ void k_node_update(const float* __restrict__ node,
                              const float* __restrict__ W2, const float* __restrict__ b2,
                              const float* __restrict__ W3, const float* __restrict__ b3,
                              const float* __restrict__ h_in, float* __restrict__ h_out) {
    __shared__ float xs[32 * DIM];
    __shared__ float ws[32 * DIM];
    int rb = blockIdx.x * 32;
    int tid = threadIdx.x;
    int tx = tid & 31;
    int ty = tid >> 5;
    float4 bv = *(const float4*)&b2[4 * tx];
    float acc[4][4];
#pragma unroll
    for (int r = 0; r < 4; ++r) {
        acc[r][0] = bv.x; acc[r][1] = bv.y; acc[r][2] = bv.z; acc[r][3] = bv.w;
    }
    for (int i = tid; i < 32 * DIM; i += 256)
        xs[i] = node[(size_t)(rb + (i >> 7)) * DIM + (i & 127)];
    for (int ks = 0; ks < 4; ++ks) {
        __syncthreads();
        for (int i = tid; i < 32 * DIM; i += 256)
            ws[i] = W2[(size_t)(ks * 32 + (i >> 7)) * DIM + (i & 127)];
        __syncthreads();
#pragma unroll
        for (int kk = 0; kk < 32; ++kk) {
            float4 w = *(const float4*)&ws[kk * DIM + 4 * tx];
            int kidx = ks * 32 + kk;
#pragma unroll
            for (int r = 0; r < 4; ++r) {
                float x = xs[(4 * ty + r) * DIM + kidx];
                acc[r][0] += x * w.x; acc[r][1] += x * w.y;
                acc[r][2] += x * w.z; acc[r][3] += x * w.w;
            }
        }
    }
    // t = sp05(acc) back into xs (done reading xs after the loop above)
    __syncthreads();
#pragma unroll
    for (int r = 0; r < 4; ++r) {
        float4 o = make_float4(sp05(acc[r][0]), sp05(acc[r][1]),
                               sp05(acc[r][2]), sp05(acc[r][3]));
        *(float4*)&xs[(4 * ty + r) * DIM + 4 * tx] = o;
    }
    float4 b3v = *(const float4*)&b3[4 * tx];
#pragma unroll
    for (int r = 0; r < 4; ++r) {
        acc[r][0] = b3v.x; acc[r][1] = b3v.y; acc[r][2] = b3v.z; acc[r][3] = b3v.w;
    }
    for (int ks = 0; ks < 4; ++ks) {
        __syncthreads();
        for (int i = tid; i < 32 * DIM; i += 256)
            ws[i] = W3[(size_t)(ks * 32 + (i >> 7)) * DIM + (i & 127)];
        __syncthreads();
#pragma unroll
        for (int kk = 0; kk < 32; ++kk) {
            float4 w = *(const float4*)&ws[kk * DIM + 4 * tx];
            int kidx = ks * 32 + kk;
#pragma unroll
            for (int r = 0; r < 4; ++r) {
                float x = xs[(4 * ty + r) * DIM + kidx];
                acc[r][0] += x * w.x; acc[r][1] += x * w.y;
                acc[r][2] += x * w.z; acc[r][3] += x * w.w;
            }
        }
    }
#pragma unroll
    for (int r = 0; r < 4; ++r) {
        size_t idx = (size_t)(rb + 4 * ty + r) * DIM + 4 * tx;
        float4 hv = *(const float4*)&h_in[idx];
        float4 o = make_float4(hv.x + acc[r][0], hv.y + acc[r][1],
                               hv.z + acc[r][2], hv.w + acc[r][3]);
        *(float4*)&h_out[idx] = o;
    }
}

// Readout, tiled: 32 rows/block, 256 threads; thread = (tx: 2 cols, ty: 4 rows).
__global__ void k_readout(const float* __restrict__ h0, const float* __restrict__ h1,
                          const float* __restrict__ h2, const float* __restrict__ h3,
                          const float* __restrict__ Wr1, const float* __restrict__ br1,
                          const float* __restrict__ Wr2, const float* __restrict__ br2,
                          const int* __restrict__ graph_ids, float* __restrict__ out) {
    __shared__ float xs[32 * DIM];   // 16 KB: one level's 32x128 tile
    __shared__ float ws[32 * 64];    // 8 KB: Wr1 k-slice
    int rb = blockIdx.x * 32;
    int tid = threadIdx.x;
    int tx = tid & 31;   // cols 2tx, 2tx+1
    int ty = tid >> 5;   // rows 4ty..4ty+3
    float2 b1 = *(const float2*)&br1[2 * tx];
    float acc[4][2];
#pragma unroll
    for (int r = 0; r < 4; ++r) { acc[r][0] = b1.x; acc[r][1] = b1.y; }
    const float* hp[4] = {h0, h1, h2, h3};
    for (int lvl = 0; lvl < 4; ++lvl) {
        __syncthreads();  // previous level's xs readers done
        for (int i = tid; i < 32 * DIM; i += 256)
            xs[i] = hp[lvl][(size_t)(rb + (i >> 7)) * DIM + (i & 127)];
        for (int ks = 0; ks < 4; ++ks) {
            __syncthreads();  // previous ws readers done (also covers xs staging)
            for (int i = tid; i < 32 * 64; i += 256)
                ws[i] = Wr1[(size_t)(lvl * DIM + ks * 32 + (i >> 6)) * 64 + (i & 63)];
            __syncthreads();
#pragma unroll
            for (int kk = 0; kk < 32; ++kk) {
                float2 w = *(const float2*)&ws[kk * 64 + 2 * tx];
                int kidx = ks * 32 + kk;
#pragma unroll
                for (int r = 0; r < 4; ++r) {
                    float x = xs[(4 * ty + r) * DIM + kidx];
                    acc[r][0] += x * w.x; acc[r][1] += x * w.y;
                }
            }
        }
    }
    float2 w2 = *(const float2*)&Wr2[2 * tx];
#pragma unroll
    for (int r = 0; r < 4; ++r) {
        float v = sp1(acc[r][0]) * w2.x + sp1(acc[r][1]) * w2.y;
#pragma unroll
        for (int off = 16; off > 0; off >>= 1) v += __shfl_xor(v, off, 32);
        if (tx == 0) {
            int n = rb + 4 * ty + r;
            atomicAdd(&out[graph_ids[n]], v + br2[0]);
        }
    }
}

extern "C" void kernel_launch(void* const* d_in, const int* in_sizes, int n_in,
                              void* d_out, int out_size, void* d_ws, size_t ws_size,
                              hipStream_t stream) {
    const int* atom_type   = (const int*)d_in[0];
    const int* src         = (const int*)d_in[1];
    const int* dst         = (const int*)d_in[2];
    const int* graph_ids   = (const int*)d_in[3];
    const float* dist      = (const float*)d_in[4];
    const float* node_emb  = (const float*)d_in[5];
    const float* W_n1 = (const float*)d_in[6];  const float* b_n1 = (const float*)d_in[7];
    const float* W_c1 = (const float*)d_in[8];  const float* b_c1 = (const float*)d_in[9];
    const float* W_c2 = (const float*)d_in[10]; const float* b_c2 = (const float*)d_in[11];
    const float* W_c3 = (const float*)d_in[12]; const float* b_c3 = (const float*)d_in[13];
    const float* W_n2 = (const float*)d_in[14]; const float* b_n2 = (const float*)d_in[15];
    const float* W_n3 = (const float*)d_in[16]; const float* b_n3 = (const float*)d_in[17];
    const float* W_r1 = (const float*)d_in[18]; const float* b_r1 = (const float*)d_in[19];
    const float* W_r2 = (const float*)d_in[20]; const float* b_r2 = (const float*)d_in[21];
    float* out = (float*)d_out;

    float* ws = (float*)d_ws;
    size_t ND = (size_t)N_NODES * DIM;
    float* hs0     = ws;
    float* hs1     = hs0 + ND;
    float* hs2     = hs1 + ND;
    float* hs3     = hs2 + ND;
    float* gbuf    = hs3 + ND;
    float* nodebuf = gbuf + ND;
    float* table   = nodebuf + ND;
    float* after_table = table + (size_t)(NBINS + 1) * DIM;
    int*   offsets = (int*)after_table;            // N_NODES+1
    int*   srcp    = offsets + (N_NODES + 1);      // N_EDGES
    int*   binp    = srcp + N_EDGES;               // N_EDGES
    float* wp      = (float*)(binp + N_EDGES);     // N_EDGES
    // temporaries aliased into nodebuf (fully rewritten by k_gather later)
    int*   counts  = (int*)nodebuf;                // N_NODES
    int*   cnt2    = counts + N_NODES;             // N_NODES
    int*   bsums   = cnt2 + N_NODES;               // NCHUNK

    float* hptr[4] = {hs0, hs1, hs2, hs3};

    hipMemsetAsync(out, 0, B_GRAPHS * sizeof(float), stream);
    hipMemsetAsync(counts, 0, (2 * N_NODES + NCHUNK) * sizeof(int), stream);

    k_embed<<<(N_NODES * DIM) / 256, 256, 0, stream>>>(atom_type, node_emb, hs0);

    // CSR build (dst-sorted edge meta)
    k_hist<<<(N_EDGES + 255) / 256, 256, 0, stream>>>(dst, counts);
    k_bsum<<<NCHUNK, 256, 0, stream>>>(counts, bsums);
    k_scan_b<<<1, 128, 0, stream>>>(bsums);
    k_scan_final<<<NCHUNK, 256, 0, stream>>>(counts, bsums, offsets);
    k_fill<<<(N_EDGES + 255) / 256, 256, 0, stream>>>(src, dst, dist, offsets, cnt2,
                                                      srcp, binp, wp);

    for (int i = 0; i < NLAYERS; ++i) {
        k_table<<<NBINS + 1, DIM, 0, stream>>>(
            W_c1 + (size_t)i * RBF_R * DIM, b_c1 + (size_t)i * DIM,
            W_c2 + (size_t)i * DIM * DIM,  b_c2 + (size_t)i * DIM,
            W_c3 + (size_t)i * DIM * DIM,  b_c3 + (size_t)i * DIM, table);
        k_gemm_g<<<N_NODES / 32, 256, 0, stream>>>(
            hptr[i], W_n1 + (size_t)i * DIM * DIM, b_n1 + (size_t)i * DIM, gbuf);
        k_gather<<<N_NODES, 128, 0, stream>>>(offsets, srcp, binp, wp, table, gbuf, nodebuf);
        k_node_update<<<N_NODES / 32, 256, 0, stream>>>(
            nodebuf, W_n2 + (size_t)i * DIM * DIM, b_n2 + (size_t)i * DIM,
            W_n3 + (size_t)i * DIM * DIM, b_n3 + (size_t)i * DIM, hptr[i], hptr[i + 1]);
    }
    k_readout<<<N_NODES / 32, 256, 0, stream>>>(
        hs0, hs1, hs2, hs3, W_r1, b_r1, W_r2, b_r2, graph_ids, out);
}

// Round 4
// 735.347 us; speedup vs baseline: 5.6270x; 1.5106x over previous
//
#include <hip/hip_runtime.h>
#include <math.h>

#define N_NODES 60000
#define N_EDGES 600000
#define B_GRAPHS 512
#define DIM 128
#define RBF_R 30
#define NLAYERS 3
#define NBINS 4096
#define CHUNK 512
#define NCHUNK ((N_NODES + CHUNK - 1) / CHUNK)   // 118

typedef __attribute__((ext_vector_type(8))) short bf16x8;
typedef __attribute__((ext_vector_type(4))) float f32x4;
typedef unsigned short ushort_t;

__device__ __forceinline__ float sp05(float x) {
    float bx = 0.5f * x;
    return bx > 14.0f ? x : 2.0f * log1pf(expf(bx));
}
__device__ __forceinline__ float sp1(float x) {
    return x > 20.0f ? x : log1pf(expf(x));
}
__device__ __forceinline__ unsigned short f2bf(float f) {
    unsigned int u = __float_as_uint(f);
    unsigned int r = u + 0x7FFFu + ((u >> 16) & 1u);  // RNE
    return (unsigned short)(r >> 16);
}
__device__ __forceinline__ float bf2f(unsigned short s) {
    return __uint_as_float(((unsigned int)s) << 16);
}

// ---------------- one-time conversion kernels ----------------

// 9 mats 128x128: W[k][n] fp32 -> Wt[n][k] bf16. mat order: Wn1 l0..2, Wn2 l0..2, Wn3 l0..2
__global__ void k_convW(const float* __restrict__ Wn1, const float* __restrict__ Wn2,
                        const float* __restrict__ Wn3, unsigned short* __restrict__ Wt) {
    int i = blockIdx.x * 256 + threadIdx.x;              // 9*16384
    int mat = i >> 14, idx = i & 16383;
    int n = idx >> 7, k = idx & 127;
    const float* src = (mat < 3) ? (Wn1 + (size_t)mat * 16384)
                     : (mat < 6) ? (Wn2 + (size_t)(mat - 3) * 16384)
                                 : (Wn3 + (size_t)(mat - 6) * 16384);
    Wt[(size_t)mat * 16384 + n * 128 + k] = f2bf(src[k * 128 + n]);
}

// Wr1 [512][64] -> Wr1t [64][512]
__global__ void k_convR(const float* __restrict__ Wr1, unsigned short* __restrict__ Wr1t) {
    int i = blockIdx.x * 256 + threadIdx.x;              // 32768
    int n = i >> 9, k = i & 511;
    Wr1t[i] = f2bf(Wr1[k * 64 + n]);
}

// h0 = node_emb[atom_type] (fp32 + bf16 copies)
__global__ void k_embed(const int* __restrict__ atom_type,
                        const float* __restrict__ node_emb,
                        float* __restrict__ h0, unsigned short* __restrict__ hb0) {
    int i = blockIdx.x * blockDim.x + threadIdx.x;
    if (i >= N_NODES * DIM) return;
    int n = i >> 7, d = i & 127;
    float v = node_emb[atom_type[n] * DIM + d];
    h0[i] = v;
    hb0[i] = f2bf(v);
}

// ---------------- CSR build (once per call) ----------------

__global__ void k_hist(const int* __restrict__ dst, int* __restrict__ counts) {
    int e = blockIdx.x * blockDim.x + threadIdx.x;
    if (e >= N_EDGES) return;
    atomicAdd(&counts[dst[e]], 1);
}

__global__ void k_bsum(const int* __restrict__ counts, int* __restrict__ bsums) {
    __shared__ int red[256];
    int c = blockIdx.x, tid = threadIdx.x;
    int base = c * CHUNK;
    int v = 0;
    for (int i = tid; i < CHUNK; i += 256)
        if (base + i < N_NODES) v += counts[base + i];
    red[tid] = v;
    __syncthreads();
    for (int s = 128; s > 0; s >>= 1) {
        if (tid < s) red[tid] += red[tid + s];
        __syncthreads();
    }
    if (tid == 0) bsums[c] = red[0];
}

__global__ void k_scan_b(int* __restrict__ bsums) {
    __shared__ int sb[NCHUNK];
    int tid = threadIdx.x;
    if (tid < NCHUNK) sb[tid] = bsums[tid];
    __syncthreads();
    if (tid == 0) {
        int run = 0;
        for (int i = 0; i < NCHUNK; ++i) { int v = sb[i]; sb[i] = run; run += v; }
    }
    __syncthreads();
    if (tid < NCHUNK) bsums[tid] = sb[tid];
}

__global__ void k_scan_final(const int* __restrict__ counts, const int* __restrict__ bsums,
                             int* __restrict__ offsets) {
    __shared__ int sc[CHUNK];
    int c = blockIdx.x, tid = threadIdx.x;
    int base = c * CHUNK;
    for (int i = tid; i < CHUNK; i += 256)
        sc[i] = (base + i < N_NODES) ? counts[base + i] : 0;
    __syncthreads();
    if (tid == 0) {
        int run = bsums[c];
        for (int i = 0; i < CHUNK; ++i) { int v = sc[i]; sc[i] = run; run += v; }
    }
    __syncthreads();
    for (int i = tid; i < CHUNK; i += 256)
        if (base + i < N_NODES) offsets[base + i] = sc[i];
    if (c == 0 && tid == 0) offsets[N_NODES] = N_EDGES;
}

__global__ void k_fill(const int* __restrict__ src, const int* __restrict__ dst,
                       const float* __restrict__ dist,
                       const int* __restrict__ offsets, int* __restrict__ cnt2,
                       int* __restrict__ srcp, int* __restrict__ binp,
                       float* __restrict__ wp) {
    int e = blockIdx.x * blockDim.x + threadIdx.x;
    if (e >= N_EDGES) return;
    int d = dst[e];
    int pos = offsets[d] + atomicAdd(&cnt2[d], 1);
    srcp[pos] = src[e];
    float x = dist[e];
    float p = x * ((float)NBINS / 10.0f);
    int bin = (int)p;
    if (bin > NBINS - 1) bin = NBINS - 1;
    binp[pos] = bin;
    wp[pos] = p - (float)bin;
}

// ---------------- per-layer kernels ----------------

// Tabulate edge MLP on 4097 bins (fp32).
__global__ void k_table(const float* __restrict__ Wc1, const float* __restrict__ bc1,
                        const float* __restrict__ Wc2, const float* __restrict__ bc2,
                        const float* __restrict__ Wc3, const float* __restrict__ bc3,
                        float* __restrict__ table) {
    __shared__ float t[DIM];
    __shared__ float u[DIM];
    int b = blockIdx.x;
    int d = threadIdx.x;
    float dist = (float)b * (10.0f / (float)NBINS);
    const float gap = 10.0f / 29.0f;
    float acc = bc1[d];
#pragma unroll
    for (int k = 0; k < RBF_R; ++k) {
        float c = (float)k * (10.0f / 29.0f);
        float df = dist - c;
        acc += expf(-df * df / gap) * Wc1[k * DIM + d];
    }
    t[d] = sp05(acc);
    __syncthreads();
    acc = bc2[d];
#pragma unroll 8
    for (int k = 0; k < DIM; ++k) acc += t[k] * Wc2[k * DIM + d];
    u[d] = acc;
    __syncthreads();
    acc = bc3[d];
#pragma unroll 8
    for (int k = 0; k < DIM; ++k) acc += u[k] * Wc3[k * DIM + d];
    table[b * DIM + d] = acc;
}

// MFMA GEMM: Cb = bf16( Ab @ Wt^T + bias + 1 ).  M=60032 grid-padded, N=K=128.
// Block: 4 waves; wave = (mhalf, nhalf): 32 rows x 64 cols; no LDS.
__global__ __launch_bounds__(256) void k_gemm_g(const unsigned short* __restrict__ Ab,
                                                const unsigned short* __restrict__ Wt,
                                                const float* __restrict__ bias,
                                                unsigned short* __restrict__ Cb) {
    int tid = threadIdx.x;
    int wave = tid >> 6, lane = tid & 63;
    int q = lane >> 4, l16 = lane & 15;
    int mhalf = wave & 1, nhalf = wave >> 1;
    int rb = blockIdx.x * 64 + mhalf * 32;
    int c0 = nhalf * 64;
    bf16x8 bfrag[4][4];
#pragma unroll
    for (int ks = 0; ks < 4; ++ks)
#pragma unroll
        for (int nt = 0; nt < 4; ++nt) {
            int n = c0 + nt * 16 + l16;
            bfrag[ks][nt] = *(const bf16x8*)&Wt[(size_t)n * 128 + ks * 32 + q * 8];
        }
    f32x4 acc[2][4] = {};
#pragma unroll
    for (int ks = 0; ks < 4; ++ks)
#pragma unroll
        for (int mt = 0; mt < 2; ++mt) {
            int m = rb + mt * 16 + l16;
            if (m > N_NODES - 1) m = N_NODES - 1;
            bf16x8 a = *(const bf16x8*)&Ab[(size_t)m * 128 + ks * 32 + q * 8];
#pragma unroll
            for (int nt = 0; nt < 4; ++nt)
                acc[mt][nt] = __builtin_amdgcn_mfma_f32_16x16x32_bf16(a, bfrag[ks][nt], acc[mt][nt], 0, 0, 0);
        }
#pragma unroll
    for (int mt = 0; mt < 2; ++mt)
#pragma unroll
        for (int nt = 0; nt < 4; ++nt) {
            int col = c0 + nt * 16 + l16;
            float b = bias[col] + 1.0f;
#pragma unroll
            for (int r = 0; r < 4; ++r) {
                int row = rb + mt * 16 + q * 4 + r;
                if (row < N_NODES) Cb[(size_t)row * 128 + col] = f2bf(acc[mt][nt][r] + b);
            }
        }
}

// Gather: one 128-thread block per node; thread d owns dim d. g is bf16 now.
__global__ void k_gather(const int* __restrict__ offsets,
                         const int* __restrict__ srcp, const int* __restrict__ binp,
                         const float* __restrict__ wp,
                         const float* __restrict__ table, const unsigned short* __restrict__ gb,
                         unsigned short* __restrict__ nodeb) {
    __shared__ int s_s[128];
    __shared__ int s_bin[128];
    __shared__ float s_w[128];
    int n = blockIdx.x;
    int d = threadIdx.x;
    int beg = offsets[n], end = offsets[n + 1];
    float acc = 0.0f;
    for (int base = beg; base < end; base += 128) {
        int cnt = min(128, end - base);
        if (d < cnt) {
            s_s[d] = srcp[base + d];
            s_bin[d] = binp[base + d];
            s_w[d] = wp[base + d];
        }
        __syncthreads();
        for (int j = 0; j < cnt; ++j) {
            int s = s_s[j];
            int bin = s_bin[j];
            float w = s_w[j];
            float a = table[(size_t)bin * DIM + d];
            float b = table[(size_t)(bin + 1) * DIM + d];
            float gv = bf2f(gb[(size_t)s * DIM + d]);
            acc += gv * (a + w * (b - a));
        }
        __syncthreads();
    }
    nodeb[(size_t)n * DIM + d] = f2bf(acc);
}

// h_out = h_in + sp05(nodeb@W2t^T + b2) @ W3t^T + b3 ; writes fp32 + bf16 copies.
__global__ __launch_bounds__(256) void k_node_update(
    const unsigned short* __restrict__ nodeb,
    const unsigned short* __restrict__ W2t, const float* __restrict__ b2,
    const unsigned short* __restrict__ W3t, const float* __restrict__ b3,
    const float* __restrict__ h_in, float* __restrict__ h_out,
    unsigned short* __restrict__ hb_out) {
    __shared__ unsigned short ts[64][136];   // +8 pad: b128 reads land 2-way max
    int tid = threadIdx.x;
    int wave = tid >> 6, lane = tid & 63;
    int q = lane >> 4, l16 = lane & 15;
    int mhalf = wave & 1, nhalf = wave >> 1;
    int rb = blockIdx.x * 64 + mhalf * 32;
    int c0 = nhalf * 64;

    bf16x8 bfrag[4][4];
#pragma unroll
    for (int ks = 0; ks < 4; ++ks)
#pragma unroll
        for (int nt = 0; nt < 4; ++nt) {
            int n = c0 + nt * 16 + l16;
            bfrag[ks][nt] = *(const bf16x8*)&W2t[(size_t)n * 128 + ks * 32 + q * 8];
        }
    f32x4 acc[2][4] = {};
#pragma unroll
    for (int ks = 0; ks < 4; ++ks)
#pragma unroll
        for (int mt = 0; mt < 2; ++mt) {
            int m = rb + mt * 16 + l16;
            if (m > N_NODES - 1) m = N_NODES - 1;
            bf16x8 a = *(const bf16x8*)&nodeb[(size_t)m * 128 + ks * 32 + q * 8];
#pragma unroll
            for (int nt = 0; nt < 4; ++nt)
                acc[mt][nt] = __builtin_amdgcn_mfma_f32_16x16x32_bf16(a, bfrag[ks][nt], acc[mt][nt], 0, 0, 0);
        }
    // t = sp05(acc + b2) -> LDS in A-layout source form (row-major, k-contiguous)
#pragma unroll
    for (int mt = 0; mt < 2; ++mt)
#pragma unroll
        for (int nt = 0; nt < 4; ++nt) {
            int col = c0 + nt * 16 + l16;
            float b = b2[col];
#pragma unroll
            for (int r = 0; r < 4; ++r) {
                int lrow = mhalf * 32 + mt * 16 + q * 4 + r;
                ts[lrow][col] = f2bf(sp05(acc[mt][nt][r] + b));
            }
        }
    __syncthreads();
    // second GEMM: t @ W3t^T
#pragma unroll
    for (int ks = 0; ks < 4; ++ks)
#pragma unroll
        for (int nt = 0; nt < 4; ++nt) {
            int n = c0 + nt * 16 + l16;
            bfrag[ks][nt] = *(const bf16x8*)&W3t[(size_t)n * 128 + ks * 32 + q * 8];
        }
#pragma unroll
    for (int mt = 0; mt < 2; ++mt)
#pragma unroll
        for (int nt = 0; nt < 4; ++nt) acc[mt][nt] = (f32x4){0.f, 0.f, 0.f, 0.f};
#pragma unroll
    for (int ks = 0; ks < 4; ++ks)
#pragma unroll
        for (int mt = 0; mt < 2; ++mt) {
            int lrow = mhalf * 32 + mt * 16 + l16;
            bf16x8 a = *(const bf16x8*)&ts[lrow][ks * 32 + q * 8];
#pragma unroll
            for (int nt = 0; nt < 4; ++nt)
                acc[mt][nt] = __builtin_amdgcn_mfma_f32_16x16x32_bf16(a, bfrag[ks][nt], acc[mt][nt], 0, 0, 0);
        }
#pragma unroll
    for (int mt = 0; mt < 2; ++mt)
#pragma unroll
        for (int nt = 0; nt < 4; ++nt) {
            int col = c0 + nt * 16 + l16;
            float b = b3[col];
#pragma unroll
            for (int r = 0; r < 4; ++r) {
                int row = rb + mt * 16 + q * 4 + r;
                if (row < N_NODES) {
                    size_t idx = (size_t)row * 128 + col;
                    float v = h_in[idx] + acc[mt][nt][r] + b;
                    h_out[idx] = v;
                    hb_out[idx] = f2bf(v);
                }
            }
        }
}

// Readout via MFMA: per 64-row block, hcat(4 levels) @ Wr1t^T -> sp1 -> .Wr2 -> atomicAdd.
__global__ __launch_bounds__(256) void k_readout(
    const unsigned short* __restrict__ hb0, const unsigned short* __restrict__ hb1,
    const unsigned short* __restrict__ hb2, const unsigned short* __restrict__ hb3,
    const unsigned short* __restrict__ Wr1t, const float* __restrict__ br1,
    const float* __restrict__ Wr2, const float* __restrict__ br2,
    const int* __restrict__ graph_ids, float* __restrict__ out) {
    int tid = threadIdx.x;
    int wave = tid >> 6, lane = tid & 63;
    int q = lane >> 4, l16 = lane & 15;
    int rb = blockIdx.x * 64 + wave * 16;
    const unsigned short* hbs[4] = {hb0, hb1, hb2, hb3};
    f32x4 acc[4] = {};
    for (int lvl = 0; lvl < 4; ++lvl) {
        bf16x8 bfrag[4][4];
#pragma unroll
        for (int ks = 0; ks < 4; ++ks)
#pragma unroll
            for (int nt = 0; nt < 4; ++nt) {
                int n = nt * 16 + l16;
                bfrag[ks][nt] = *(const bf16x8*)&Wr1t[(size_t)n * 512 + lvl * 128 + ks * 32 + q * 8];
            }
        const unsigned short* Ab = hbs[lvl];
#pragma unroll
        for (int ks = 0; ks < 4; ++ks) {
            int m = rb + l16;
            if (m > N_NODES - 1) m = N_NODES - 1;
            bf16x8 a = *(const bf16x8*)&Ab[(size_t)m * 128 + ks * 32 + q * 8];
#pragma unroll
            for (int nt = 0; nt < 4; ++nt)
                acc[nt] = __builtin_amdgcn_mfma_f32_16x16x32_bf16(a, bfrag[ks][nt], acc[nt], 0, 0, 0);
        }
    }
    float partial[4] = {0.f, 0.f, 0.f, 0.f};
#pragma unroll
    for (int nt = 0; nt < 4; ++nt) {
        int col = nt * 16 + l16;
        float b = br1[col];
        float w = Wr2[col];
#pragma unroll
        for (int r = 0; r < 4; ++r) partial[r] += sp1(acc[nt][r] + b) * w;
    }
    float brr = br2[0];
#pragma unroll
    for (int r = 0; r < 4; ++r) {
        float v = partial[r];
        v += __shfl_xor(v, 1); v += __shfl_xor(v, 2);
        v += __shfl_xor(v, 4); v += __shfl_xor(v, 8);
        if (l16 == 0) {
            int row = rb + q * 4 + r;
            if (row < N_NODES) atomicAdd(&out[graph_ids[row]], v + brr);
        }
    }
}

extern "C" void kernel_launch(void* const* d_in, const int* in_sizes, int n_in,
                              void* d_out, int out_size, void* d_ws, size_t ws_size,
                              hipStream_t stream) {
    const int* atom_type   = (const int*)d_in[0];
    const int* src         = (const int*)d_in[1];
    const int* dst         = (const int*)d_in[2];
    const int* graph_ids   = (const int*)d_in[3];
    const float* dist      = (const float*)d_in[4];
    const float* node_emb  = (const float*)d_in[5];
    const float* W_n1 = (const float*)d_in[6];  const float* b_n1 = (const float*)d_in[7];
    const float* W_c1 = (const float*)d_in[8];  const float* b_c1 = (const float*)d_in[9];
    const float* W_c2 = (const float*)d_in[10]; const float* b_c2 = (const float*)d_in[11];
    const float* W_c3 = (const float*)d_in[12]; const float* b_c3 = (const float*)d_in[13];
    const float* W_n2 = (const float*)d_in[14]; const float* b_n2 = (const float*)d_in[15];
    const float* W_n3 = (const float*)d_in[16]; const float* b_n3 = (const float*)d_in[17];
    const float* W_r1 = (const float*)d_in[18]; const float* b_r1 = (const float*)d_in[19];
    const float* W_r2 = (const float*)d_in[20]; const float* b_r2 = (const float*)d_in[21];
    float* out = (float*)d_out;

    size_t ND = (size_t)N_NODES * DIM;   // 7,680,000
    // float region
    float* h_even = (float*)d_ws;
    float* h_odd  = h_even + ND;
    float* table  = h_odd + ND;                         // 4097*128 = 524416
    float* wp     = table + (size_t)(NBINS + 1) * DIM;  // 600000
    // int region
    int* offsets  = (int*)(wp + N_EDGES);               // 60008 (padded)
    int* srcp     = offsets + 60008;                    // 600000
    int* binp     = srcp + N_EDGES;                     // 600000
    int* counts   = binp + N_EDGES;                     // 60000
    int* cnt2     = counts + N_NODES;                   // 60000
    int* bsums    = cnt2 + N_NODES;                     // 128 (padded)
    // ushort region
    unsigned short* hb0   = (unsigned short*)(bsums + 128);
    unsigned short* hb1   = hb0 + ND;
    unsigned short* hb2   = hb1 + ND;
    unsigned short* hb3   = hb2 + ND;
    unsigned short* gb    = hb3 + ND;
    unsigned short* nodeb = gb + ND;
    unsigned short* Wt    = nodeb + ND;                 // 9*16384
    unsigned short* Wr1t  = Wt + 9 * 16384;             // 64*512

    unsigned short* hbp[4] = {hb0, hb1, hb2, hb3};
    float* hcur = h_even;
    float* hnext = h_odd;

    hipMemsetAsync(out, 0, B_GRAPHS * sizeof(float), stream);
    hipMemsetAsync(counts, 0, (2 * N_NODES + 128) * sizeof(int), stream);

    k_convW<<<(9 * 16384) / 256, 256, 0, stream>>>(W_n1, W_n2, W_n3, Wt);
    k_convR<<<32768 / 256, 256, 0, stream>>>(W_r1, Wr1t);
    k_embed<<<(N_NODES * DIM) / 256, 256, 0, stream>>>(atom_type, node_emb, h_even, hb0);

    // CSR build (dst-sorted edge meta)
    k_hist<<<(N_EDGES + 255) / 256, 256, 0, stream>>>(dst, counts);
    k_bsum<<<NCHUNK, 256, 0, stream>>>(counts, bsums);
    k_scan_b<<<1, 128, 0, stream>>>(bsums);
    k_scan_final<<<NCHUNK, 256, 0, stream>>>(counts, bsums, offsets);
    k_fill<<<(N_EDGES + 255) / 256, 256, 0, stream>>>(src, dst, dist, offsets, cnt2,
                                                      srcp, binp, wp);

    int gblocks = (N_NODES + 63) / 64;   // 938
    for (int i = 0; i < NLAYERS; ++i) {
        k_table<<<NBINS + 1, DIM, 0, stream>>>(
            W_c1 + (size_t)i * RBF_R * DIM, b_c1 + (size_t)i * DIM,
            W_c2 + (size_t)i * DIM * DIM,  b_c2 + (size_t)i * DIM,
            W_c3 + (size_t)i * DIM * DIM,  b_c3 + (size_t)i * DIM, table);
        k_gemm_g<<<gblocks, 256, 0, stream>>>(
            hbp[i], Wt + (size_t)i * 16384, b_n1 + (size_t)i * DIM, gb);
        k_gather<<<N_NODES, 128, 0, stream>>>(offsets, srcp, binp, wp, table, gb, nodeb);
        k_node_update<<<gblocks, 256, 0, stream>>>(
            nodeb, Wt + (size_t)(3 + i) * 16384, b_n2 + (size_t)i * DIM,
            Wt + (size_t)(6 + i) * 16384, b_n3 + (size_t)i * DIM,
            hcur, hnext, hbp[i + 1]);
        float* tmp = hcur; hcur = hnext; hnext = tmp;
    }
    k_readout<<<gblocks, 256, 0, stream>>>(
        hb0, hb1, hb2, hb3, Wr1t, b_r1, W_r2, b_r2, graph_ids, out);
}

// Round 5
// 658.053 us; speedup vs baseline: 6.2879x; 1.1175x over previous
//
#include <hip/hip_runtime.h>
#include <math.h>

#define N_NODES 60000
#define N_EDGES 600000
#define B_GRAPHS 512
#define DIM 128
#define RBF_R 30
#define NLAYERS 3
#define NBINS 4096
#define CHUNK 512
#define NCHUNK ((N_NODES + CHUNK - 1) / CHUNK)   // 118

typedef __attribute__((ext_vector_type(8))) short bf16x8;
typedef __attribute__((ext_vector_type(4))) float f32x4;

__device__ __forceinline__ float sp05(float x) {
    float bx = 0.5f * x;
    return bx > 14.0f ? x : 2.0f * log1pf(expf(bx));
}
__device__ __forceinline__ float sp1(float x) {
    return x > 20.0f ? x : log1pf(expf(x));
}
__device__ __forceinline__ unsigned short f2bf(float f) {
    unsigned int u = __float_as_uint(f);
    unsigned int r = u + 0x7FFFu + ((u >> 16) & 1u);  // RNE
    return (unsigned short)(r >> 16);
}
__device__ __forceinline__ float bf2f(unsigned short s) {
    return __uint_as_float(((unsigned int)s) << 16);
}

// ---------------- one-time conversion kernels ----------------
// Fragment-order layout: each MFMA B-fragment (64 lanes x 16B = 512 bf16) is
// stored contiguously so the per-wave bfrag load is ONE coalesced 1KB read.

// 9 mats 128x128 -> fragment order. frag=(ks,ntile): WtF[mat][ks*8+ntile][lane*8+j]
//   = W[k=ks*32+(lane>>4)*8+j][n=ntile*16+(lane&15)]
__global__ void k_convW(const float* __restrict__ Wn1, const float* __restrict__ Wn2,
                        const float* __restrict__ Wn3, unsigned short* __restrict__ WtF) {
    int i = blockIdx.x * 256 + threadIdx.x;              // 9*16384
    int mat = i >> 14, r = i & 16383;
    int frag = r >> 9, within = r & 511;
    int ks = frag >> 3, ntile = frag & 7;
    int lane = within >> 3, j = within & 7;
    int q = lane >> 4, l16 = lane & 15;
    int n = ntile * 16 + l16;
    int k = ks * 32 + q * 8 + j;
    const float* src = (mat < 3) ? (Wn1 + (size_t)mat * 16384)
                     : (mat < 6) ? (Wn2 + (size_t)(mat - 3) * 16384)
                                 : (Wn3 + (size_t)(mat - 6) * 16384);
    WtF[i] = f2bf(src[k * 128 + n]);
}

// Wr1 [512][64] -> fragment order: frag=(lvl,ks,ntile) 4*4*4=64 frags of 512.
__global__ void k_convR(const float* __restrict__ Wr1, unsigned short* __restrict__ Wr1tF) {
    int i = blockIdx.x * 256 + threadIdx.x;              // 32768
    int frag = i >> 9, within = i & 511;
    int lvl = frag >> 4, ks = (frag >> 2) & 3, ntile = frag & 3;
    int lane = within >> 3, j = within & 7;
    int q = lane >> 4, l16 = lane & 15;
    int n = ntile * 16 + l16;
    int k = lvl * 128 + ks * 32 + q * 8 + j;
    Wr1tF[i] = f2bf(Wr1[k * 64 + n]);
}

// h0 = node_emb[atom_type] (fp32 + bf16 copies)
__global__ void k_embed(const int* __restrict__ atom_type,
                        const float* __restrict__ node_emb,
                        float* __restrict__ h0, unsigned short* __restrict__ hb0) {
    int i = blockIdx.x * blockDim.x + threadIdx.x;
    if (i >= N_NODES * DIM) return;
    int n = i >> 7, d = i & 127;
    float v = node_emb[atom_type[n] * DIM + d];
    h0[i] = v;
    hb0[i] = f2bf(v);
}

// ---------------- CSR build (once per call) ----------------

__global__ void k_hist(const int* __restrict__ dst, int* __restrict__ counts) {
    int e = blockIdx.x * blockDim.x + threadIdx.x;
    if (e >= N_EDGES) return;
    atomicAdd(&counts[dst[e]], 1);
}

__global__ void k_bsum(const int* __restrict__ counts, int* __restrict__ bsums) {
    __shared__ int red[256];
    int c = blockIdx.x, tid = threadIdx.x;
    int base = c * CHUNK;
    int v = 0;
    for (int i = tid; i < CHUNK; i += 256)
        if (base + i < N_NODES) v += counts[base + i];
    red[tid] = v;
    __syncthreads();
    for (int s = 128; s > 0; s >>= 1) {
        if (tid < s) red[tid] += red[tid + s];
        __syncthreads();
    }
    if (tid == 0) bsums[c] = red[0];
}

__global__ void k_scan_b(int* __restrict__ bsums) {
    __shared__ int sb[NCHUNK];
    int tid = threadIdx.x;
    if (tid < NCHUNK) sb[tid] = bsums[tid];
    __syncthreads();
    if (tid == 0) {
        int run = 0;
        for (int i = 0; i < NCHUNK; ++i) { int v = sb[i]; sb[i] = run; run += v; }
    }
    __syncthreads();
    if (tid < NCHUNK) bsums[tid] = sb[tid];
}

__global__ void k_scan_final(const int* __restrict__ counts, const int* __restrict__ bsums,
                             int* __restrict__ offsets) {
    __shared__ int sc[CHUNK];
    int c = blockIdx.x, tid = threadIdx.x;
    int base = c * CHUNK;
    for (int i = tid; i < CHUNK; i += 256)
        sc[i] = (base + i < N_NODES) ? counts[base + i] : 0;
    __syncthreads();
    if (tid == 0) {
        int run = bsums[c];
        for (int i = 0; i < CHUNK; ++i) { int v = sc[i]; sc[i] = run; run += v; }
    }
    __syncthreads();
    for (int i = tid; i < CHUNK; i += 256)
        if (base + i < N_NODES) offsets[base + i] = sc[i];
    if (c == 0 && tid == 0) offsets[N_NODES] = N_EDGES;
}

__global__ void k_fill(const int* __restrict__ src, const int* __restrict__ dst,
                       const float* __restrict__ dist,
                       const int* __restrict__ offsets, int* __restrict__ cnt2,
                       int* __restrict__ srcp, int* __restrict__ binp,
                       float* __restrict__ wp) {
    int e = blockIdx.x * blockDim.x + threadIdx.x;
    if (e >= N_EDGES) return;
    int d = dst[e];
    int pos = offsets[d] + atomicAdd(&cnt2[d], 1);
    srcp[pos] = src[e];
    float x = dist[e];
    float p = x * ((float)NBINS / 10.0f);
    int bin = (int)p;
    if (bin > NBINS - 1) bin = NBINS - 1;
    binp[pos] = bin;
    wp[pos] = p - (float)bin;
}

// ---------------- per-layer kernels ----------------

// Tabulate edge MLP on 4097 bins -> bf16 table.
__global__ void k_table(const float* __restrict__ Wc1, const float* __restrict__ bc1,
                        const float* __restrict__ Wc2, const float* __restrict__ bc2,
                        const float* __restrict__ Wc3, const float* __restrict__ bc3,
                        unsigned short* __restrict__ tableb) {
    __shared__ float t[DIM];
    __shared__ float u[DIM];
    int b = blockIdx.x;
    int d = threadIdx.x;
    float dist = (float)b * (10.0f / (float)NBINS);
    const float gap = 10.0f / 29.0f;
    float acc = bc1[d];
#pragma unroll
    for (int k = 0; k < RBF_R; ++k) {
        float c = (float)k * (10.0f / 29.0f);
        float df = dist - c;
        acc += expf(-df * df / gap) * Wc1[k * DIM + d];
    }
    t[d] = sp05(acc);
    __syncthreads();
    acc = bc2[d];
#pragma unroll 8
    for (int k = 0; k < DIM; ++k) acc += t[k] * Wc2[k * DIM + d];
    u[d] = acc;
    __syncthreads();
    acc = bc3[d];
#pragma unroll 8
    for (int k = 0; k < DIM; ++k) acc += u[k] * Wc3[k * DIM + d];
    tableb[b * DIM + d] = f2bf(acc);
}

// MFMA GEMM: Cb = bf16( Ab @ W^T + bias + 1 ). Fragment-order B.
__global__ __launch_bounds__(256) void k_gemm_g(const unsigned short* __restrict__ Ab,
                                                const unsigned short* __restrict__ WtF,
                                                const float* __restrict__ bias,
                                                unsigned short* __restrict__ Cb) {
    int tid = threadIdx.x;
    int wave = tid >> 6, lane = tid & 63;
    int q = lane >> 4, l16 = lane & 15;
    int mhalf = wave & 1, nhalf = wave >> 1;
    int rb = blockIdx.x * 64 + mhalf * 32;
    int c0 = nhalf * 64;
    bf16x8 bfrag[4][4];
#pragma unroll
    for (int ks = 0; ks < 4; ++ks)
#pragma unroll
        for (int nt = 0; nt < 4; ++nt)
            bfrag[ks][nt] = *(const bf16x8*)&WtF[(size_t)(ks * 8 + nhalf * 4 + nt) * 512 + lane * 8];
    f32x4 acc[2][4] = {};
#pragma unroll
    for (int ks = 0; ks < 4; ++ks)
#pragma unroll
        for (int mt = 0; mt < 2; ++mt) {
            int m = rb + mt * 16 + l16;
            if (m > N_NODES - 1) m = N_NODES - 1;
            bf16x8 a = *(const bf16x8*)&Ab[(size_t)m * 128 + ks * 32 + q * 8];
#pragma unroll
            for (int nt = 0; nt < 4; ++nt)
                acc[mt][nt] = __builtin_amdgcn_mfma_f32_16x16x32_bf16(a, bfrag[ks][nt], acc[mt][nt], 0, 0, 0);
        }
#pragma unroll
    for (int mt = 0; mt < 2; ++mt)
#pragma unroll
        for (int nt = 0; nt < 4; ++nt) {
            int col = c0 + nt * 16 + l16;
            float b = bias[col] + 1.0f;
#pragma unroll
            for (int r = 0; r < 4; ++r) {
                int row = rb + mt * 16 + q * 4 + r;
                if (row < N_NODES) Cb[(size_t)row * 128 + col] = f2bf(acc[mt][nt][r] + b);
            }
        }
}

// Gather: one 128-thread block per node; thread d owns dim d. table + g bf16.
__global__ void k_gather(const int* __restrict__ offsets,
                         const int* __restrict__ srcp, const int* __restrict__ binp,
                         const float* __restrict__ wp,
                         const unsigned short* __restrict__ tableb,
                         const unsigned short* __restrict__ gb,
                         unsigned short* __restrict__ nodeb) {
    __shared__ int s_s[128];
    __shared__ int s_bin[128];
    __shared__ float s_w[128];
    int n = blockIdx.x;
    int d = threadIdx.x;
    int beg = offsets[n], end = offsets[n + 1];
    float acc = 0.0f;
    for (int base = beg; base < end; base += 128) {
        int cnt = min(128, end - base);
        if (d < cnt) {
            s_s[d] = srcp[base + d];
            s_bin[d] = binp[base + d];
            s_w[d] = wp[base + d];
        }
        __syncthreads();
        for (int j = 0; j < cnt; ++j) {
            int s = s_s[j];
            int bin = s_bin[j];
            float w = s_w[j];
            float a = bf2f(tableb[(size_t)bin * DIM + d]);
            float b = bf2f(tableb[(size_t)(bin + 1) * DIM + d]);
            float gv = bf2f(gb[(size_t)s * DIM + d]);
            acc += gv * (a + w * (b - a));
        }
        __syncthreads();
    }
    nodeb[(size_t)n * DIM + d] = f2bf(acc);
}

// h_out = h_in + sp05(nodeb@W2^T + b2) @ W3^T + b3 ; fp32 + bf16 outputs.
__global__ __launch_bounds__(256) void k_node_update(
    const unsigned short* __restrict__ nodeb,
    const unsigned short* __restrict__ W2tF, const float* __restrict__ b2,
    const unsigned short* __restrict__ W3tF, const float* __restrict__ b3,
    const float* __restrict__ h_in, float* __restrict__ h_out,
    unsigned short* __restrict__ hb_out) {
    __shared__ unsigned short ts[64][136];
    int tid = threadIdx.x;
    int wave = tid >> 6, lane = tid & 63;
    int q = lane >> 4, l16 = lane & 15;
    int mhalf = wave & 1, nhalf = wave >> 1;
    int rb = blockIdx.x * 64 + mhalf * 32;
    int c0 = nhalf * 64;

    bf16x8 bfrag[4][4];
#pragma unroll
    for (int ks = 0; ks < 4; ++ks)
#pragma unroll
        for (int nt = 0; nt < 4; ++nt)
            bfrag[ks][nt] = *(const bf16x8*)&W2tF[(size_t)(ks * 8 + nhalf * 4 + nt) * 512 + lane * 8];
    f32x4 acc[2][4] = {};
#pragma unroll
    for (int ks = 0; ks < 4; ++ks)
#pragma unroll
        for (int mt = 0; mt < 2; ++mt) {
            int m = rb + mt * 16 + l16;
            if (m > N_NODES - 1) m = N_NODES - 1;
            bf16x8 a = *(const bf16x8*)&nodeb[(size_t)m * 128 + ks * 32 + q * 8];
#pragma unroll
            for (int nt = 0; nt < 4; ++nt)
                acc[mt][nt] = __builtin_amdgcn_mfma_f32_16x16x32_bf16(a, bfrag[ks][nt], acc[mt][nt], 0, 0, 0);
        }
#pragma unroll
    for (int mt = 0; mt < 2; ++mt)
#pragma unroll
        for (int nt = 0; nt < 4; ++nt) {
            int col = c0 + nt * 16 + l16;
            float b = b2[col];
#pragma unroll
            for (int r = 0; r < 4; ++r) {
                int lrow = mhalf * 32 + mt * 16 + q * 4 + r;
                ts[lrow][col] = f2bf(sp05(acc[mt][nt][r] + b));
            }
        }
    __syncthreads();
#pragma unroll
    for (int ks = 0; ks < 4; ++ks)
#pragma unroll
        for (int nt = 0; nt < 4; ++nt)
            bfrag[ks][nt] = *(const bf16x8*)&W3tF[(size_t)(ks * 8 + nhalf * 4 + nt) * 512 + lane * 8];
#pragma unroll
    for (int mt = 0; mt < 2; ++mt)
#pragma unroll
        for (int nt = 0; nt < 4; ++nt) acc[mt][nt] = (f32x4){0.f, 0.f, 0.f, 0.f};
#pragma unroll
    for (int ks = 0; ks < 4; ++ks)
#pragma unroll
        for (int mt = 0; mt < 2; ++mt) {
            int lrow = mhalf * 32 + mt * 16 + l16;
            bf16x8 a = *(const bf16x8*)&ts[lrow][ks * 32 + q * 8];
#pragma unroll
            for (int nt = 0; nt < 4; ++nt)
                acc[mt][nt] = __builtin_amdgcn_mfma_f32_16x16x32_bf16(a, bfrag[ks][nt], acc[mt][nt], 0, 0, 0);
        }
#pragma unroll
    for (int mt = 0; mt < 2; ++mt)
#pragma unroll
        for (int nt = 0; nt < 4; ++nt) {
            int col = c0 + nt * 16 + l16;
            float b = b3[col];
#pragma unroll
            for (int r = 0; r < 4; ++r) {
                int row = rb + mt * 16 + q * 4 + r;
                if (row < N_NODES) {
                    size_t idx = (size_t)row * 128 + col;
                    float v = h_in[idx] + acc[mt][nt][r] + b;
                    h_out[idx] = v;
                    hb_out[idx] = f2bf(v);
                }
            }
        }
}

// Readout: 128 rows/block (2 m-tiles per wave), fragment-order Wr1.
__global__ __launch_bounds__(256) void k_readout(
    const unsigned short* __restrict__ hb0, const unsigned short* __restrict__ hb1,
    const unsigned short* __restrict__ hb2, const unsigned short* __restrict__ hb3,
    const unsigned short* __restrict__ Wr1tF, const float* __restrict__ br1,
    const float* __restrict__ Wr2, const float* __restrict__ br2,
    const int* __restrict__ graph_ids, float* __restrict__ out) {
    int tid = threadIdx.x;
    int wave = tid >> 6, lane = tid & 63;
    int q = lane >> 4, l16 = lane & 15;
    int rb0 = blockIdx.x * 128 + wave * 16;   // m-tile mt at rb0 + mt*64
    const unsigned short* hbs[4] = {hb0, hb1, hb2, hb3};
    f32x4 acc[2][4] = {};
    for (int lvl = 0; lvl < 4; ++lvl) {
        bf16x8 bfrag[4][4];
#pragma unroll
        for (int ks = 0; ks < 4; ++ks)
#pragma unroll
            for (int nt = 0; nt < 4; ++nt)
                bfrag[ks][nt] = *(const bf16x8*)&Wr1tF[(size_t)((lvl * 4 + ks) * 4 + nt) * 512 + lane * 8];
        const unsigned short* Ab = hbs[lvl];
#pragma unroll
        for (int ks = 0; ks < 4; ++ks)
#pragma unroll
            for (int mt = 0; mt < 2; ++mt) {
                int m = rb0 + mt * 64 + l16;
                if (m > N_NODES - 1) m = N_NODES - 1;
                bf16x8 a = *(const bf16x8*)&Ab[(size_t)m * 128 + ks * 32 + q * 8];
#pragma unroll
                for (int nt = 0; nt < 4; ++nt)
                    acc[mt][nt] = __builtin_amdgcn_mfma_f32_16x16x32_bf16(a, bfrag[ks][nt], acc[mt][nt], 0, 0, 0);
            }
    }
    float brr = br2[0];
#pragma unroll
    for (int mt = 0; mt < 2; ++mt) {
        float partial[4] = {0.f, 0.f, 0.f, 0.f};
#pragma unroll
        for (int nt = 0; nt < 4; ++nt) {
            int col = nt * 16 + l16;
            float b = br1[col];
            float w = Wr2[col];
#pragma unroll
            for (int r = 0; r < 4; ++r) partial[r] += sp1(acc[mt][nt][r] + b) * w;
        }
#pragma unroll
        for (int r = 0; r < 4; ++r) {
            float v = partial[r];
            v += __shfl_xor(v, 1); v += __shfl_xor(v, 2);
            v += __shfl_xor(v, 4); v += __shfl_xor(v, 8);
            if (l16 == 0) {
                int row = rb0 + mt * 64 + q * 4 + r;
                if (row < N_NODES) atomicAdd(&out[graph_ids[row]], v + brr);
            }
        }
    }
}

extern "C" void kernel_launch(void* const* d_in, const int* in_sizes, int n_in,
                              void* d_out, int out_size, void* d_ws, size_t ws_size,
                              hipStream_t stream) {
    const int* atom_type   = (const int*)d_in[0];
    const int* src         = (const int*)d_in[1];
    const int* dst         = (const int*)d_in[2];
    const int* graph_ids   = (const int*)d_in[3];
    const float* dist      = (const float*)d_in[4];
    const float* node_emb  = (const float*)d_in[5];
    const float* W_n1 = (const float*)d_in[6];  const float* b_n1 = (const float*)d_in[7];
    const float* W_c1 = (const float*)d_in[8];  const float* b_c1 = (const float*)d_in[9];
    const float* W_c2 = (const float*)d_in[10]; const float* b_c2 = (const float*)d_in[11];
    const float* W_c3 = (const float*)d_in[12]; const float* b_c3 = (const float*)d_in[13];
    const float* W_n2 = (const float*)d_in[14]; const float* b_n2 = (const float*)d_in[15];
    const float* W_n3 = (const float*)d_in[16]; const float* b_n3 = (const float*)d_in[17];
    const float* W_r1 = (const float*)d_in[18]; const float* b_r1 = (const float*)d_in[19];
    const float* W_r2 = (const float*)d_in[20]; const float* b_r2 = (const float*)d_in[21];
    float* out = (float*)d_out;

    size_t ND = (size_t)N_NODES * DIM;   // 7,680,000
    // float region
    float* h_even = (float*)d_ws;
    float* h_odd  = h_even + ND;
    float* wp     = h_odd + ND;                          // 600000
    // int region
    int* offsets  = (int*)(wp + N_EDGES);               // 60008 (padded)
    int* srcp     = offsets + 60008;                    // 600000
    int* binp     = srcp + N_EDGES;                     // 600000
    int* counts   = binp + N_EDGES;                     // 60000
    int* cnt2     = counts + N_NODES;                   // 60000
    int* bsums    = cnt2 + N_NODES;                     // 128 (padded)
    // ushort region
    unsigned short* hb0    = (unsigned short*)(bsums + 128);
    unsigned short* hb1    = hb0 + ND;
    unsigned short* hb2    = hb1 + ND;
    unsigned short* hb3    = hb2 + ND;
    unsigned short* gb     = hb3 + ND;
    unsigned short* nodeb  = gb + ND;
    unsigned short* tableb = nodeb + ND;                // 4097*128 = 524416
    unsigned short* WtF    = tableb + (size_t)(NBINS + 1) * DIM;  // 9*16384
    unsigned short* Wr1tF  = WtF + 9 * 16384;           // 32768

    unsigned short* hbp[4] = {hb0, hb1, hb2, hb3};
    float* hcur = h_even;
    float* hnext = h_odd;

    hipMemsetAsync(out, 0, B_GRAPHS * sizeof(float), stream);
    hipMemsetAsync(counts, 0, (2 * N_NODES + 128) * sizeof(int), stream);

    k_convW<<<(9 * 16384) / 256, 256, 0, stream>>>(W_n1, W_n2, W_n3, WtF);
    k_convR<<<32768 / 256, 256, 0, stream>>>(W_r1, Wr1tF);
    k_embed<<<(N_NODES * DIM) / 256, 256, 0, stream>>>(atom_type, node_emb, h_even, hb0);

    // CSR build (dst-sorted edge meta)
    k_hist<<<(N_EDGES + 255) / 256, 256, 0, stream>>>(dst, counts);
    k_bsum<<<NCHUNK, 256, 0, stream>>>(counts, bsums);
    k_scan_b<<<1, 128, 0, stream>>>(bsums);
    k_scan_final<<<NCHUNK, 256, 0, stream>>>(counts, bsums, offsets);
    k_fill<<<(N_EDGES + 255) / 256, 256, 0, stream>>>(src, dst, dist, offsets, cnt2,
                                                      srcp, binp, wp);

    int gblocks = (N_NODES + 63) / 64;      // 938
    int rblocks = (N_NODES + 127) / 128;    // 469
    for (int i = 0; i < NLAYERS; ++i) {
        k_table<<<NBINS + 1, DIM, 0, stream>>>(
            W_c1 + (size_t)i * RBF_R * DIM, b_c1 + (size_t)i * DIM,
            W_c2 + (size_t)i * DIM * DIM,  b_c2 + (size_t)i * DIM,
            W_c3 + (size_t)i * DIM * DIM,  b_c3 + (size_t)i * DIM, tableb);
        k_gemm_g<<<gblocks, 256, 0, stream>>>(
            hbp[i], WtF + (size_t)i * 16384, b_n1 + (size_t)i * DIM, gb);
        k_gather<<<N_NODES, 128, 0, stream>>>(offsets, srcp, binp, wp, tableb, gb, nodeb);
        k_node_update<<<gblocks, 256, 0, stream>>>(
            nodeb, WtF + (size_t)(3 + i) * 16384, b_n2 + (size_t)i * DIM,
            WtF + (size_t)(6 + i) * 16384, b_n3 + (size_t)i * DIM,
            hcur, hnext, hbp[i + 1]);
        float* tmp = hcur; hcur = hnext; hnext = tmp;
    }
    k_readout<<<rblocks, 256, 0, stream>>>(
        hb0, hb1, hb2, hb3, Wr1tF, b_r1, W_r2, b_r2, graph_ids, out);
}